// Round 10
// baseline (76.075 us; speedup 1.0000x reference)
//
#include <hip/hip_runtime.h>
#include <hip/hip_bf16.h>

#define BB 16
#define LCTX 2048
#define DDIM 1024
#define QDIM 1024
#define HDIM 256

typedef __attribute__((ext_vector_type(8))) short short8;
typedef __attribute__((ext_vector_type(4))) short short4v;
typedef __attribute__((ext_vector_type(4))) float f32x4;

__device__ inline unsigned short f2bf(float x) {
    unsigned int u = __float_as_uint(x);
    unsigned int r = (u + 0x7fffu + ((u >> 16) & 1u)) >> 16;
    return (unsigned short)r;
}

// ---------------- K1: fused prep ----------------
// bid <  1024 : qproj[b][h] = query[b] . Wq[h] + b1[h]
// 1024..1279  : Wc row (h) -> bf16 k-major: Wc_kmaj[kt][h][64]  (R6-verified)
// bid == 1280 : w2 = g * v / ||v||
__global__ __launch_bounds__(256) void k_prep(const float* __restrict__ query,
                                              const float* __restrict__ W1,
                                              const float* __restrict__ b1,
                                              const float* __restrict__ v,
                                              const float* __restrict__ g,
                                              float* __restrict__ qproj,
                                              unsigned short* __restrict__ Wc_kmaj,
                                              float* __restrict__ w2) {
    int bid = blockIdx.x;
    if (bid < 1024) {
        int b = bid >> 6;
        int hq = bid & 63;
        int wid = threadIdx.x >> 6, lane = threadIdx.x & 63;
        int h = hq * 4 + wid;
        const float* q = query + b * QDIM;
        const float* w = W1 + (size_t)h * (DDIM + QDIM) + DDIM;
        float s = 0.f;
        #pragma unroll 4
        for (int k = lane; k < QDIM; k += 64) s += q[k] * w[k];
        #pragma unroll
        for (int o = 32; o; o >>= 1) s += __shfl_down(s, o);
        if (lane == 0) qproj[b * HDIM + h] = s + b1[h];
    } else if (bid < 1280) {
        int h = bid - 1024;
        const float* src = W1 + (size_t)h * (DDIM + QDIM);
        for (int d = threadIdx.x; d < DDIM; d += 256) {
            int kt = d >> 6;
            int ko = d & 63;
            Wc_kmaj[(size_t)kt * 16384 + h * 64 + ko] = f2bf(src[d]);
        }
    } else {
        __shared__ float red[256];
        float vv = (threadIdx.x < HDIM) ? v[threadIdx.x] : 0.f;
        red[threadIdx.x] = vv * vv;
        __syncthreads();
        for (int o = 128; o; o >>= 1) {
            if (threadIdx.x < o) red[threadIdx.x] += red[threadIdx.x + o];
            __syncthreads();
        }
        float nrm = sqrtf(red[0]);
        if (threadIdx.x < HDIM) w2[threadIdx.x] = g[0] * vv / nrm;
    }
}

// ---------------- K2: barrier-light GEMM ----------------
// B (W) straight global->reg from k-major layout (L2-hot, no LDS, no coupling).
// A (ctx) via dbuf 2x8KB LDS, R9 contiguous staging; sync = raw s_barrier +
// own-wave lgkmcnt(0) ONLY. No vmcnt drains: compiler counts per-use, so
// A(t+1)/B(t) global loads stay in flight across the barrier.
__global__ __launch_bounds__(256, 2) void k_score(const float* __restrict__ ctx,
                                                  const unsigned short* __restrict__ Wc_kmaj,
                                                  const float* __restrict__ qproj,
                                                  const float* __restrict__ w2,
                                                  const float* __restrict__ b2p,
                                                  const int* __restrict__ mask,
                                                  float* __restrict__ e_ws,
                                                  float* __restrict__ esum_ws,
                                                  float* __restrict__ part) {
    __shared__ unsigned short At[2][64 * 64];   // 2 x 8 KB dbuf, XOR-swizzled
    int tid = threadIdx.x;
    int wid = tid >> 6, lane = tid & 63;
    int hl = lane & 15, lhi = lane >> 4;
    int bid = blockIdx.x;
    int row0 = bid * 64;
    int b = row0 >> 11;

    f32x4 acc[4][4];
    #pragma unroll
    for (int mt = 0; mt < 4; mt++)
        #pragma unroll
        for (int ht = 0; ht < 4; ht++)
            acc[mt][ht] = (f32x4){0.f, 0.f, 0.f, 0.f};

    // A staging map (R9-verified): instr i covers rows srow_base + i*4 (4 full
    // contiguous 256B rows per wave-instr = 16 lines)
    int srow_base = wid * 16 + lhi;             // + i*4
    int scol = (lane & 15) * 4;                 // float col within 64-col k-tile
    int chunk = (lane & 15) >> 1;               // 16B chunk idx 0..7
    int half8 = (lane & 1) * 4;                 // 8B half (elements)

    // B base: Wc_kmaj + kt*16384 + h*64 + (ks*4+lhi)*8 ; h = wid*64 + ht*16 + hl
    const unsigned short* bbase = Wc_kmaj + (size_t)(wid * 64 + hl) * 64 + lhi * 8;

    float4 xa0, xa1, xa2, xa3, ya0, ya1, ya2, ya3;

#define LOAD_A(KT, R0, R1, R2, R3) do { \
    const float* cp_ = ctx + (size_t)(row0 + srow_base) * DDIM + (KT) * 64 + scol; \
    R0 = *(const float4*)(cp_);                    \
    R1 = *(const float4*)(cp_ + 4 * DDIM);         \
    R2 = *(const float4*)(cp_ + 8 * DDIM);         \
    R3 = *(const float4*)(cp_ + 12 * DDIM); } while (0)

#define WRITE_A(BUF, R0, R1, R2, R3) do { \
    short4v h0_ = { (short)f2bf(R0.x), (short)f2bf(R0.y), (short)f2bf(R0.z), (short)f2bf(R0.w) }; \
    short4v h1_ = { (short)f2bf(R1.x), (short)f2bf(R1.y), (short)f2bf(R1.z), (short)f2bf(R1.w) }; \
    short4v h2_ = { (short)f2bf(R2.x), (short)f2bf(R2.y), (short)f2bf(R2.z), (short)f2bf(R2.w) }; \
    short4v h3_ = { (short)f2bf(R3.x), (short)f2bf(R3.y), (short)f2bf(R3.z), (short)f2bf(R3.w) }; \
    int r0_ = srow_base;                                                     \
    *(short4v*)(&At[BUF][(r0_     ) * 64 + ((chunk ^ ((r0_     ) & 7)) << 3) + half8]) = h0_; \
    *(short4v*)(&At[BUF][(r0_ +  4) * 64 + ((chunk ^ ((r0_ + 4) & 7)) << 3) + half8]) = h1_; \
    *(short4v*)(&At[BUF][(r0_ +  8) * 64 + ((chunk ^ ((r0_ + 8) & 7)) << 3) + half8]) = h2_; \
    *(short4v*)(&At[BUF][(r0_ + 12) * 64 + ((chunk ^ ((r0_ +12) & 7)) << 3) + half8]) = h3_; } while (0)

#define BODY(KT, DO_A, C0, C1, C2, C3, N0, N1, N2, N3) do { \
    if (DO_A) { LOAD_A((KT) + 1, N0, N1, N2, N3); } \
    WRITE_A((KT) & 1, C0, C1, C2, C3); \
    asm volatile("s_waitcnt lgkmcnt(0)" ::: "memory"); \
    __builtin_amdgcn_s_barrier(); \
    __builtin_amdgcn_sched_barrier(0); \
    _Pragma("unroll") \
    for (int ks_ = 0; ks_ < 2; ks_++) { \
        int s_ = ks_ * 4 + lhi; \
        short8 af_[4], bf_[4]; \
        _Pragma("unroll") \
        for (int mt_ = 0; mt_ < 4; mt_++) { \
            int m_ = mt_ * 16 + hl; \
            af_[mt_] = *(const short8*)(&At[(KT) & 1][m_ * 64 + ((s_ ^ (m_ & 7)) << 3)]); \
        } \
        _Pragma("unroll") \
        for (int ht_ = 0; ht_ < 4; ht_++) \
            bf_[ht_] = *(const short8*)(bbase + (size_t)(KT) * 16384 + ht_ * 1024 + ks_ * 32); \
        __builtin_amdgcn_s_setprio(1); \
        _Pragma("unroll") \
        for (int mt_ = 0; mt_ < 4; mt_++) \
            _Pragma("unroll") \
            for (int ht_ = 0; ht_ < 4; ht_++) \
                acc[mt_][ht_] = __builtin_amdgcn_mfma_f32_16x16x32_bf16(af_[mt_], bf_[ht_], acc[mt_][ht_], 0, 0, 0); \
        __builtin_amdgcn_s_setprio(0); \
    } \
    __builtin_amdgcn_s_barrier(); } while (0)

    LOAD_A(0, xa0, xa1, xa2, xa3);

    BODY( 0, 1,  xa0, xa1, xa2, xa3,  ya0, ya1, ya2, ya3);
    BODY( 1, 1,  ya0, ya1, ya2, ya3,  xa0, xa1, xa2, xa3);
    BODY( 2, 1,  xa0, xa1, xa2, xa3,  ya0, ya1, ya2, ya3);
    BODY( 3, 1,  ya0, ya1, ya2, ya3,  xa0, xa1, xa2, xa3);
    BODY( 4, 1,  xa0, xa1, xa2, xa3,  ya0, ya1, ya2, ya3);
    BODY( 5, 1,  ya0, ya1, ya2, ya3,  xa0, xa1, xa2, xa3);
    BODY( 6, 1,  xa0, xa1, xa2, xa3,  ya0, ya1, ya2, ya3);
    BODY( 7, 1,  ya0, ya1, ya2, ya3,  xa0, xa1, xa2, xa3);
    BODY( 8, 1,  xa0, xa1, xa2, xa3,  ya0, ya1, ya2, ya3);
    BODY( 9, 1,  ya0, ya1, ya2, ya3,  xa0, xa1, xa2, xa3);
    BODY(10, 1,  xa0, xa1, xa2, xa3,  ya0, ya1, ya2, ya3);
    BODY(11, 1,  ya0, ya1, ya2, ya3,  xa0, xa1, xa2, xa3);
    BODY(12, 1,  xa0, xa1, xa2, xa3,  ya0, ya1, ya2, ya3);
    BODY(13, 1,  ya0, ya1, ya2, ya3,  xa0, xa1, xa2, xa3);
    BODY(14, 1,  xa0, xa1, xa2, xa3,  ya0, ya1, ya2, ya3);
    BODY(15, 0,  ya0, ya1, ya2, ya3,  xa0, xa1, xa2, xa3);

    __syncthreads();

    // ---- epilogue 1: tanh + w2 dot, reduce 16 lanes, cross-wave via LDS ----
    float qp[4], wv[4];
    #pragma unroll
    for (int ht = 0; ht < 4; ht++) {
        int h = wid * 64 + ht * 16 + hl;
        qp[ht] = qproj[b * HDIM + h];
        wv[ht] = w2[h];
    }
    float* sb  = (float*)At;        // 256 floats (cross-wave partials)
    float* sbe = sb + 256;          // 64 floats (e per row)
    #pragma unroll
    for (int mt = 0; mt < 4; mt++) {
        #pragma unroll
        for (int r = 0; r < 4; r++) {
            float partial = 0.f;
            #pragma unroll
            for (int ht = 0; ht < 4; ht++) {
                float x = acc[mt][ht][r] + qp[ht];
                x = fminf(fmaxf(x, -15.f), 15.f);
                float e2 = __expf(2.f * x);
                partial += (e2 - 1.f) / (e2 + 1.f) * wv[ht];
            }
            #pragma unroll
            for (int o = 1; o < 16; o <<= 1) partial += __shfl_xor(partial, o);
            if (hl == 0) sb[wid * 64 + mt * 16 + lhi * 4 + r] = partial;
        }
    }
    __syncthreads();

    // ---- epilogue 2: score -> e = exp(score) (masked -> 0) ----
    if (tid < 64) {
        float s = sb[tid] + sb[64 + tid] + sb[128 + tid] + sb[192 + tid] + b2p[0];
        int grow = row0 + tid;
        float e = (mask[b * 2048 + (grow & 2047)] == 1) ? 0.f : __expf(s);
        e_ws[grow] = e;
        sbe[tid] = e;
        float tot = e;
        #pragma unroll
        for (int o = 32; o; o >>= 1) tot += __shfl_down(tot, o);
        if (tid == 0) esum_ws[bid] = tot;
    }
    __syncthreads();

    // ---- epilogue 3: fused partial GEMV (tile L2/L3-hot) ----
    {
        int d0 = tid * 4;
        const float* cb = ctx + (size_t)row0 * DDIM + d0;
        float4 a = {0.f, 0.f, 0.f, 0.f};
        #pragma unroll 8
        for (int l = 0; l < 64; l++) {
            float el = sbe[l];
            float4 cc = *(const float4*)(cb + (size_t)l * DDIM);
            a.x += el * cc.x; a.y += el * cc.y; a.z += el * cc.z; a.w += el * cc.w;
        }
        *(float4*)(part + (size_t)bid * DDIM + d0) = a;
    }
}

// ---------------- K3: normalize -> out_exp, out_p ----------------
__global__ __launch_bounds__(256) void k_norm(const float* __restrict__ e_ws,
                                              const float* __restrict__ esum_ws,
                                              const float* __restrict__ part,
                                              float* __restrict__ out_exp,
                                              float* __restrict__ out_p) {
    int b = blockIdx.x, dc = blockIdx.y;
    int tid = threadIdx.x;
    float se = 0.f;
    #pragma unroll
    for (int j = 0; j < 32; j++) se += esum_ws[b * 32 + j];
    float inv = 1.f / se;
    if (tid < 128) {
        int d = dc * 128 + tid;
        float s = 0.f;
        #pragma unroll
        for (int j = 0; j < 32; j++) s += part[(size_t)(b * 32 + j) * DDIM + d];
        out_exp[b * DDIM + d] = s * inv;
    }
    int l = dc * 256 + tid;
    out_p[b * LCTX + l] = e_ws[b * LCTX + l] * inv;
}

extern "C" void kernel_launch(void* const* d_in, const int* in_sizes, int n_in,
                              void* d_out, int out_size, void* d_ws, size_t ws_size,
                              hipStream_t stream) {
    const float* ctx   = (const float*)d_in[0];
    const float* query = (const float*)d_in[1];
    const int*   mask  = (const int*)d_in[2];
    const float* W1    = (const float*)d_in[3];
    const float* b1    = (const float*)d_in[4];
    const float* v     = (const float*)d_in[5];
    const float* g     = (const float*)d_in[6];
    const float* b2    = (const float*)d_in[7];
    float* out_exp = (float*)d_out;              // [16,1024]
    float* out_p   = (float*)d_out + 16384;      // [16,2048]

    char* ws = (char*)d_ws;
    unsigned short* Wc_kmaj = (unsigned short*)ws;        // 512 KB
    float* qproj = (float*)(ws + 524288);                 // 16 KB
    float* w2    = (float*)(ws + 540672);                 // 1 KB
    float* e_ws  = (float*)(ws + 541696);                 // 128 KB (16x2048)
    float* esum  = (float*)(ws + 672768);                 // 2 KB  (512)
    float* part  = (float*)(ws + 674816);                 // 2 MB  (512x1024)

    k_prep <<<dim3(1281),   256, 0, stream>>>(query, W1, b1, v, g, qproj, Wc_kmaj, w2);
    k_score<<<dim3(512),    256, 0, stream>>>(ctx, Wc_kmaj, qproj, w2, b2, mask, e_ws, esum, part);
    k_norm <<<dim3(16, 8),  256, 0, stream>>>(e_ws, esum, part, out_exp, out_p);
}